// Round 2
// baseline (656.635 us; speedup 1.0000x reference)
//
#include <hip/hip_runtime.h>
#include <math.h>

// Problem constants (match the jax reference)
constexpr int B_  = 2;
constexpr int C_  = 64;
constexpr int HW_ = 64 * 128;      // 8192
constexpr int N_  = HW_;           // points per image (near == far == 8192)
constexpr int NX_ = 512;
constexpr int NY_ = 512;
constexpr int NYNX_ = NX_ * NY_;   // 262144
constexpr int SEG_ = 8;            // near-loop segments per far point
constexpr int FPB_ = 32;           // far points per block (32 far x 8 seg = 256 thr)

// ---------------------------------------------------------------------------
// Pack points. near4/far4: (x,y,z,validflag) for the scatter.
// nearnn: (x,y,z, w) where w = |p|^2 in exact numpy-f32 rounding for valid
// points, or -1.0f for masked points (reference replaces their d2 with 1e10).
// ---------------------------------------------------------------------------
__global__ __launch_bounds__(256) void pack_kernel(
    const float* __restrict__ pi, const int* __restrict__ pm,
    const float* __restrict__ pif, const int* __restrict__ pmf,
    float4* __restrict__ near4, float4* __restrict__ far4,
    float4* __restrict__ nearnn) {
#pragma clang fp contract(off)
  int t = blockIdx.x * 256 + threadIdx.x;        // over B_*N_
  int k = t / N_, n = t % N_;
  const float* base  = pi  + (size_t)k * 4 * HW_;
  const float* basef = pif + (size_t)k * 4 * HW_;
  float x = base[n], y = base[HW_ + n], z = base[2 * HW_ + n];
  bool v = pm[k * HW_ + n] > 0;
  near4[t] = make_float4(x, y, z, v ? 1.0f : 0.0f);
  // numpy: sum(p*p, -1) over 3 elems = ((x*x + y*y) + z*z), each op f32-rounded
  float sq = (x * x + y * y) + z * z;
  nearnn[t] = make_float4(x, y, z, v ? sq : -1.0f);
  far4[t] = make_float4(basef[n], basef[HW_ + n], basef[2 * HW_ + n],
                        pmf[k * HW_ + n] > 0 ? 1.0f : 0.0f);
}

// ---------------------------------------------------------------------------
// Transpose fv (B,C,HW) -> fvT (B,HW,C).
// ---------------------------------------------------------------------------
__global__ __launch_bounds__(256) void transpose_kernel(
    const float* __restrict__ fv, float* __restrict__ fvT) {
  __shared__ float tile[64][65];
  int tx = threadIdx.x & 63, ty = threadIdx.x >> 6;
  int k = blockIdx.y, n0 = blockIdx.x * 64;
  for (int c = ty; c < C_; c += 4)
    tile[c][tx] = fv[((size_t)(k * C_ + c)) * HW_ + n0 + tx];
  __syncthreads();
  for (int nn = ty; nn < 64; nn += 4)
    fvT[((size_t)(k * HW_ + n0 + nn)) * C_ + tx] = tile[tx][nn];
}

// ---------------------------------------------------------------------------
// Top-3 insertion, b0<=b1<=b2; strict < keeps the earliest-inserted on ties
// (== lowest index when candidates arrive in ascending index order), matching
// a stable descending sort of -d2 (jax.lax.top_k tie rule).
// ---------------------------------------------------------------------------
__device__ inline void ins3f(float t, int n,
                             float& b0, float& b1, float& b2,
                             int& i0, int& i1, int& i2) {
  if (t < b2) {
    if (t < b1) {
      b2 = b1; i2 = i1;
      if (t < b0) { b1 = b0; i1 = i0; b0 = t; i0 = n; }
      else        { b1 = t;  i1 = n; }
    } else { b2 = t; i2 = n; }
  }
}

// ---------------------------------------------------------------------------
// Brute-force 3-NN replicating the reference's f32 arithmetic bitwise:
//   d2 = (sum(far^2) + sum(near^2)) - dot(2*far, near)
// with dot = single-accumulator ascending-k FMA chain (BLAS sgemm microkernel
// order: fma(az,bz, fma(ay,by, round(ax*bx)))). Masked near -> 1e10f.
// ---------------------------------------------------------------------------
__global__ __launch_bounds__(256) void nn_kernel(
    const float4* __restrict__ nearnn, const float4* __restrict__ far4,
    int* __restrict__ nn_idx, float* __restrict__ nn_w) {
#pragma clang fp contract(off)
  int tid = threadIdx.x;
  int fl = tid & (FPB_ - 1);      // far-local 0..31
  int s  = tid >> 5;              // segment 0..7
  int k  = blockIdx.y;
  int m  = blockIdx.x * FPB_ + fl;

  float4 fp = far4[k * N_ + m];
  float fx = fp.x, fy = fp.y, fz = fp.z;
  float sf = (fx * fx + fy * fy) + fz * fz;       // numpy 3-elem sum order
  float ax = 2.0f * fx, ay = 2.0f * fy, az = 2.0f * fz;  // (2.0*far), exact

  float b0 = 1e30f, b1 = 1e30f, b2 = 1e30f;
  int j0 = 0, j1 = 0, j2 = 0;
  constexpr int SEGN = N_ / SEG_;  // 1024
  const float4* np4 = nearnn + k * N_ + s * SEGN;
  for (int i = 0; i < SEGN; ++i) {
    float4 q = np4[i];
    float p0 = ax * q.x;                          // round(ax*bx)
    float mm = __builtin_fmaf(az, q.z, __builtin_fmaf(ay, q.y, p0));
    float t = (q.w >= 0.0f) ? ((sf + q.w) - mm) : 1e10f;
    ins3f(t, s * SEGN + i, b0, b1, b2, j0, j1, j2);
  }

  __shared__ float sd[FPB_][SEG_][3];
  __shared__ int   si[FPB_][SEG_][3];
  sd[fl][s][0] = b0; sd[fl][s][1] = b1; sd[fl][s][2] = b2;
  si[fl][s][0] = j0; si[fl][s][1] = j1; si[fl][s][2] = j2;
  __syncthreads();

  if (s == 0) {
    float c0 = 1e30f, c1 = 1e30f, c2 = 1e30f;
    int i0 = 0, i1 = 0, i2 = 0;
    for (int ss = 0; ss < SEG_; ++ss)
      for (int j = 0; j < 3; ++j)
        ins3f(sd[fl][ss][j], si[fl][ss][j], c0, c1, c2, i0, i1, i2);
    // weights exactly as reference (f32): 1/(d+1e-8), normalized by (r0+r1)+r2
    float r0 = 1.0f / (c0 + 1e-8f);
    float r1 = 1.0f / (c1 + 1e-8f);
    float r2 = 1.0f / (c2 + 1e-8f);
    float rs = (r0 + r1) + r2;
    int o = (k * N_ + m) * 3;
    nn_idx[o + 0] = i0; nn_idx[o + 1] = i1; nn_idx[o + 2] = i2;
    nn_w[o + 0] = r0 / rs;
    nn_w[o + 1] = r1 / rs;
    nn_w[o + 2] = r2 / rs;
  }
}

// ---------------------------------------------------------------------------
// Scatter-add point features into out (B,C,NY,NX) + counts. One wave per
// point; lane = channel. Voxel binning replicates numpy f32 bitwise:
// floor((x - lo_f32) / 0.1f) with IEEE f32 sub/div, no contraction.
// ---------------------------------------------------------------------------
__global__ __launch_bounds__(256) void scatter_kernel(
    const float4* __restrict__ near4, const float4* __restrict__ far4,
    const float* __restrict__ fvT,
    const int* __restrict__ nn_idx, const float* __restrict__ nn_w,
    float* __restrict__ out, float* __restrict__ cnt) {
#pragma clang fp contract(off)
  int lane = threadIdx.x & 63;
  int wv = blockIdx.x * 4 + (threadIdx.x >> 6);  // global wave id = point slot
  int k = wv / (2 * N_);
  int p = wv % (2 * N_);
  bool is_far = p >= N_;
  int n = is_far ? p - N_ : p;

  float4 pt = is_far ? far4[k * N_ + n] : near4[k * N_ + n];
  if (pt.w == 0.0f) return;  // invalid: zero weight in reference scatter

  float qx = (pt.x - 0.0f) / 0.1f;      // f32 IEEE ops, match numpy bitwise
  float qy = (pt.y - (-25.6f)) / 0.1f;
  int ix = (int)floorf(qx);
  int iy = (int)floorf(qy);
  if (ix < 0 || ix >= NX_ || iy < 0 || iy >= NY_) return;
  int v = iy * NX_ + ix;

  float val;
  if (!is_far) {
    val = fvT[((size_t)(k * N_ + n)) * C_ + lane];
  } else {
    int o = (k * N_ + n) * 3;
    int i0 = nn_idx[o], i1 = nn_idx[o + 1], i2 = nn_idx[o + 2];
    float w0 = nn_w[o], w1 = nn_w[o + 1], w2 = nn_w[o + 2];
    val = w0 * fvT[((size_t)(k * N_ + i0)) * C_ + lane]
        + w1 * fvT[((size_t)(k * N_ + i1)) * C_ + lane]
        + w2 * fvT[((size_t)(k * N_ + i2)) * C_ + lane];
  }
  atomicAdd(&out[((size_t)(k * C_ + lane)) * NYNX_ + v], val);
  if (lane == 0) atomicAdd(&cnt[(size_t)k * NYNX_ + v], 1.0f);
}

// ---------------------------------------------------------------------------
// Mean division. cnt in {0,1} -> identity, so only touch cnt >= 2 voxels.
// ---------------------------------------------------------------------------
__global__ __launch_bounds__(256) void finalize_kernel(
    float* __restrict__ out, const float* __restrict__ cnt) {
  int t = blockIdx.x * 256 + threadIdx.x;  // over B_*NYNX_
  int k = t / NYNX_, v = t % NYNX_;
  float c = cnt[(size_t)k * NYNX_ + v];
  if (c >= 2.0f) {
    for (int cc = 0; cc < C_; ++cc)
      out[((size_t)(k * C_ + cc)) * NYNX_ + v] /= c;
  }
}

extern "C" void kernel_launch(void* const* d_in, const int* in_sizes, int n_in,
                              void* d_out, int out_size, void* d_ws, size_t ws_size,
                              hipStream_t stream) {
  const float* fv  = (const float*)d_in[0];  // (B,C,H,W)
  const float* pi  = (const float*)d_in[1];  // (B,4,H,W)
  const int*   pm  = (const int*)d_in[2];    // (B,H,W)
  const float* pif = (const float*)d_in[3];  // (B,4,H,W)
  const int*   pmf = (const int*)d_in[4];    // (B,H,W)
  float* out = (float*)d_out;                // (B,C,NY,NX) f32

  // workspace layout (16B aligned), total ~7.5 MB
  char* wsb = (char*)d_ws;
  float*  fvT    = (float*)(wsb);                 // B*HW*C*4      = 4,194,304
  float*  cnt    = (float*)(wsb + 4194304);       // B*NYNX*4      = 2,097,152
  float4* near4  = (float4*)(wsb + 6291456);      // B*N*16        =   262,144
  float4* far4   = (float4*)(wsb + 6553600);      // B*N*16        =   262,144
  float4* nearnn = (float4*)(wsb + 6815744);      // B*N*16        =   262,144
  int*    nnidx  = (int*)(wsb + 7077888);         // B*N*3*4       =   196,608
  float*  nnw    = (float*)(wsb + 7274496);       // B*N*3*4       =   196,608

  hipMemsetAsync(out, 0, (size_t)out_size * sizeof(float), stream);
  hipMemsetAsync(cnt, 0, (size_t)B_ * NYNX_ * sizeof(float), stream);

  pack_kernel<<<B_ * N_ / 256, 256, 0, stream>>>(pi, pm, pif, pmf, near4, far4, nearnn);
  transpose_kernel<<<dim3(HW_ / 64, B_), 256, 0, stream>>>(fv, fvT);
  nn_kernel<<<dim3(N_ / FPB_, B_), 256, 0, stream>>>(nearnn, far4, nnidx, nnw);
  scatter_kernel<<<B_ * 2 * N_ / 4, 256, 0, stream>>>(near4, far4, fvT, nnidx, nnw, out, cnt);
  finalize_kernel<<<B_ * NYNX_ / 256, 256, 0, stream>>>(out, cnt);
}

// Round 4
// 359.456 us; speedup vs baseline: 1.8267x; 1.8267x over previous
//
#include <hip/hip_runtime.h>
#include <math.h>

// Problem constants (match the jax reference)
constexpr int B_  = 2;
constexpr int C_  = 64;
constexpr int HW_ = 64 * 128;      // 8192
constexpr int N_  = HW_;           // points per image (near == far == 8192)
constexpr int NX_ = 512;
constexpr int NY_ = 512;
constexpr int NYNX_ = NX_ * NY_;   // 262144
constexpr int SEG_ = 8;            // near-dim segments (partial top-3 per seg)
constexpr int SEGN_ = N_ / SEG_;   // 1024 near candidates per segment

// ---------------------------------------------------------------------------
// Pack points. near4/far4: (x,y,z,validflag) for the scatter.
// nearnn: (x,y,z,w) with w = |p|^2 in exact numpy-f32 order for valid points,
// or -1.0f for masked points (reference replaces their d2 with 1e10).
// ---------------------------------------------------------------------------
__global__ __launch_bounds__(256) void pack_kernel(
    const float* __restrict__ pi, const int* __restrict__ pm,
    const float* __restrict__ pif, const int* __restrict__ pmf,
    float4* __restrict__ near4, float4* __restrict__ far4,
    float4* __restrict__ nearnn) {
#pragma clang fp contract(off)
  int t = blockIdx.x * 256 + threadIdx.x;        // over B_*N_
  int k = t / N_, n = t % N_;
  const float* base  = pi  + (size_t)k * 4 * HW_;
  const float* basef = pif + (size_t)k * 4 * HW_;
  float x = base[n], y = base[HW_ + n], z = base[2 * HW_ + n];
  bool v = pm[k * HW_ + n] > 0;
  near4[t] = make_float4(x, y, z, v ? 1.0f : 0.0f);
  float sq = (x * x + y * y) + z * z;   // numpy 3-elem sum order
  nearnn[t] = make_float4(x, y, z, v ? sq : -1.0f);
  far4[t] = make_float4(basef[n], basef[HW_ + n], basef[2 * HW_ + n],
                        pmf[k * HW_ + n] > 0 ? 1.0f : 0.0f);
}

// ---------------------------------------------------------------------------
// Transpose fv (B,C,HW) -> fvT (B,HW,C).
// ---------------------------------------------------------------------------
__global__ __launch_bounds__(256) void transpose_kernel(
    const float* __restrict__ fv, float* __restrict__ fvT) {
  __shared__ float tile[64][65];
  int tx = threadIdx.x & 63, ty = threadIdx.x >> 6;
  int k = blockIdx.y, n0 = blockIdx.x * 64;
  for (int c = ty; c < C_; c += 4)
    tile[c][tx] = fv[((size_t)(k * C_ + c)) * HW_ + n0 + tx];
  __syncthreads();
  for (int nn = ty; nn < 64; nn += 4)
    fvT[((size_t)(k * HW_ + n0 + nn)) * C_ + tx] = tile[tx][nn];
}

// ---------------------------------------------------------------------------
// Branchless stable insert of (tv, idx) into sorted top-3 (b0<=b1<=b2).
// Exactly reproduces the verified R2 sequential ins3f (jax stable top-k):
//   c0 = tv<b0, c1 = tv<b1, c2 = tv<b2  (c0 => c1 => c2 by sortedness)
//   b0' = c0?tv:b0;  b1' = c0?b0:(c1?tv:b1);  b2' = c1?b1:(c2?tv:b2)
// New candidate LOSES ties (strict <); displaced incumbents shift down
// unconditionally WITH their indices (this was the R3 merge3 tie bug).
// ---------------------------------------------------------------------------
__device__ __forceinline__ void merge3(float tv, int idx,
                                       float& b0, float& b1, float& b2,
                                       int& i0, int& i1, int& i2) {
  bool c0 = tv < b0;
  bool c1 = tv < b1;
  bool c2 = tv < b2;
  float ob0 = b0, ob1 = b1;
  int   oi0 = i0, oi1 = i1;
  b0 = c0 ? tv : b0;                    i0 = c0 ? idx : i0;
  b1 = c0 ? ob0 : (c1 ? tv : b1);       i1 = c0 ? oi0 : (c1 ? idx : i1);
  b2 = c1 ? ob1 : (c2 ? tv : b2);       i2 = c1 ? oi1 : (c2 ? idx : i2);
}

// ---------------------------------------------------------------------------
// Partial 3-NN: block = (far-block fb, near-segment s, batch k). Each thread
// owns one far point; the 1024-candidate segment is staged in LDS and read
// broadcast (conflict-free). d2 replicates the reference f32 arithmetic
// bitwise: (sf + sq_near) - fma(az,qz, fma(ay,qy, ax*qx)).
// ---------------------------------------------------------------------------
__global__ __launch_bounds__(256) void nn_part_kernel(
    const float4* __restrict__ nearnn, const float4* __restrict__ far4,
    float* __restrict__ pd, int* __restrict__ pidx) {
#pragma clang fp contract(off)
  __shared__ float4 tile[SEGN_];
  int t = threadIdx.x;
  int fb = blockIdx.x;           // 0..31  far block
  int s  = blockIdx.y;           // 0..SEG_-1
  int k  = blockIdx.z;           // batch

  const float4* src = nearnn + k * N_ + s * SEGN_;
  for (int r = 0; r < SEGN_ / 256; ++r)
    tile[t + 256 * r] = src[t + 256 * r];
  __syncthreads();

  int m = fb * 256 + t;
  float4 fp = far4[k * N_ + m];
  float fx = fp.x, fy = fp.y, fz = fp.z;
  float sf = (fx * fx + fy * fy) + fz * fz;              // numpy 3-elem order
  float ax = 2.0f * fx, ay = 2.0f * fy, az = 2.0f * fz;  // (2.0*far), exact

  float b0 = 1e30f, b1 = 1e30f, b2 = 1e30f;
  int i0 = 0, i1 = 0, i2 = 0;
  int base_idx = s * SEGN_;
#pragma unroll 4
  for (int i = 0; i < SEGN_; ++i) {
    float4 q = tile[i];
    float p0 = ax * q.x;                                  // round(ax*qx)
    float mm = __builtin_fmaf(az, q.z, __builtin_fmaf(ay, q.y, p0));
    float d2 = (sf + q.w) - mm;
    float tv = (q.w >= 0.0f) ? d2 : 1e10f;                // masked -> BIG
    merge3(tv, base_idx + i, b0, b1, b2, i0, i1, i2);
  }

  int o = ((k * N_ + m) * SEG_ + s) * 3;
  pd[o] = b0; pd[o + 1] = b1; pd[o + 2] = b2;
  pidx[o] = i0; pidx[o + 1] = i1; pidx[o + 2] = i2;
}

// ---------------------------------------------------------------------------
// Merge the SEG_ partial top-3 lists per far point (segment-ascending order
// preserves lowest-index tie-breaking) and compute weights exactly as R2.
// ---------------------------------------------------------------------------
__global__ __launch_bounds__(256) void nn_merge_kernel(
    const float* __restrict__ pd, const int* __restrict__ pidx,
    int* __restrict__ nn_idx, float* __restrict__ nn_w) {
#pragma clang fp contract(off)
  int g = blockIdx.x * 256 + threadIdx.x;   // 0..B_*N_-1
  const float* dp = pd + (size_t)g * SEG_ * 3;
  const int*   ip = pidx + (size_t)g * SEG_ * 3;
  float b0 = 1e30f, b1 = 1e30f, b2 = 1e30f;
  int i0 = 0, i1 = 0, i2 = 0;
  for (int j = 0; j < SEG_ * 3; ++j)
    merge3(dp[j], ip[j], b0, b1, b2, i0, i1, i2);
  float r0 = 1.0f / (b0 + 1e-8f);
  float r1 = 1.0f / (b1 + 1e-8f);
  float r2 = 1.0f / (b2 + 1e-8f);
  float rs = (r0 + r1) + r2;
  int o = g * 3;
  nn_idx[o] = i0; nn_idx[o + 1] = i1; nn_idx[o + 2] = i2;
  nn_w[o] = r0 / rs; nn_w[o + 1] = r1 / rs; nn_w[o + 2] = r2 / rs;
}

// ---------------------------------------------------------------------------
// Scatter-add point features into out (B,C,NY,NX) + counts. One wave per
// point; lane = channel. Voxel binning in f32 IEEE ops, matching numpy.
// ---------------------------------------------------------------------------
__global__ __launch_bounds__(256) void scatter_kernel(
    const float4* __restrict__ near4, const float4* __restrict__ far4,
    const float* __restrict__ fvT,
    const int* __restrict__ nn_idx, const float* __restrict__ nn_w,
    float* __restrict__ out, float* __restrict__ cnt) {
#pragma clang fp contract(off)
  int lane = threadIdx.x & 63;
  int wv = blockIdx.x * 4 + (threadIdx.x >> 6);  // global wave id = point slot
  int k = wv / (2 * N_);
  int p = wv % (2 * N_);
  bool is_far = p >= N_;
  int n = is_far ? p - N_ : p;

  float4 pt = is_far ? far4[k * N_ + n] : near4[k * N_ + n];
  if (pt.w == 0.0f) return;  // invalid: zero weight in reference scatter

  float qx = (pt.x - 0.0f) / 0.1f;
  float qy = (pt.y - (-25.6f)) / 0.1f;
  int ix = (int)floorf(qx);
  int iy = (int)floorf(qy);
  if (ix < 0 || ix >= NX_ || iy < 0 || iy >= NY_) return;
  int v = iy * NX_ + ix;

  float val;
  if (!is_far) {
    val = fvT[((size_t)(k * N_ + n)) * C_ + lane];
  } else {
    int o = (k * N_ + n) * 3;
    int i0 = nn_idx[o], i1 = nn_idx[o + 1], i2 = nn_idx[o + 2];
    float w0 = nn_w[o], w1 = nn_w[o + 1], w2 = nn_w[o + 2];
    val = w0 * fvT[((size_t)(k * N_ + i0)) * C_ + lane]
        + w1 * fvT[((size_t)(k * N_ + i1)) * C_ + lane]
        + w2 * fvT[((size_t)(k * N_ + i2)) * C_ + lane];
  }
  atomicAdd(&out[((size_t)(k * C_ + lane)) * NYNX_ + v], val);
  if (lane == 0) atomicAdd(&cnt[(size_t)k * NYNX_ + v], 1.0f);
}

// ---------------------------------------------------------------------------
// Mean division. cnt in {0,1} -> identity, so only touch cnt >= 2 voxels.
// ---------------------------------------------------------------------------
__global__ __launch_bounds__(256) void finalize_kernel(
    float* __restrict__ out, const float* __restrict__ cnt) {
  int t = blockIdx.x * 256 + threadIdx.x;  // over B_*NYNX_
  int k = t / NYNX_, v = t % NYNX_;
  float c = cnt[(size_t)k * NYNX_ + v];
  if (c >= 2.0f) {
    for (int cc = 0; cc < C_; ++cc)
      out[((size_t)(k * C_ + cc)) * NYNX_ + v] /= c;
  }
}

extern "C" void kernel_launch(void* const* d_in, const int* in_sizes, int n_in,
                              void* d_out, int out_size, void* d_ws, size_t ws_size,
                              hipStream_t stream) {
  const float* fv  = (const float*)d_in[0];  // (B,C,H,W)
  const float* pi  = (const float*)d_in[1];  // (B,4,H,W)
  const int*   pm  = (const int*)d_in[2];    // (B,H,W)
  const float* pif = (const float*)d_in[3];  // (B,4,H,W)
  const int*   pmf = (const int*)d_in[4];    // (B,H,W)
  float* out = (float*)d_out;                // (B,C,NY,NX) f32

  // workspace layout (16B aligned), total ~7.5 MB
  char* wsb = (char*)d_ws;
  float*  fvT    = (float*)(wsb);                 // B*HW*C*4      = 4,194,304
  float*  cnt    = (float*)(wsb + 4194304);       // B*NYNX*4      = 2,097,152
  float4* near4  = (float4*)(wsb + 6291456);      // B*N*16        =   262,144
  float4* far4   = (float4*)(wsb + 6553600);      // B*N*16        =   262,144
  float4* nearnn = (float4*)(wsb + 6815744);      // B*N*16        =   262,144
  int*    nnidx  = (int*)(wsb + 7077888);         // B*N*3*4       =   196,608
  float*  nnw    = (float*)(wsb + 7274496);       // B*N*3*4       =   196,608

  // Partial top-3 buffers live in d_out's head (dead until the memset below):
  // pd: B*N*SEG_*3 floats = 1.57 MB, pidx same in ints.
  float* pd   = out;
  int*   pidx = (int*)(out + (size_t)B_ * N_ * SEG_ * 3);

  pack_kernel<<<B_ * N_ / 256, 256, 0, stream>>>(pi, pm, pif, pmf, near4, far4, nearnn);
  transpose_kernel<<<dim3(HW_ / 64, B_), 256, 0, stream>>>(fv, fvT);
  nn_part_kernel<<<dim3(N_ / 256, SEG_, B_), 256, 0, stream>>>(nearnn, far4, pd, pidx);
  nn_merge_kernel<<<B_ * N_ / 256, 256, 0, stream>>>(pd, pidx, nnidx, nnw);

  hipMemsetAsync(out, 0, (size_t)out_size * sizeof(float), stream);
  hipMemsetAsync(cnt, 0, (size_t)B_ * NYNX_ * sizeof(float), stream);

  scatter_kernel<<<B_ * 2 * N_ / 4, 256, 0, stream>>>(near4, far4, fvT, nnidx, nnw, out, cnt);
  finalize_kernel<<<B_ * NYNX_ / 256, 256, 0, stream>>>(out, cnt);
}

// Round 5
// 315.638 us; speedup vs baseline: 2.0803x; 1.1388x over previous
//
#include <hip/hip_runtime.h>
#include <math.h>

// Problem constants (match the jax reference)
constexpr int B_  = 2;
constexpr int C_  = 64;
constexpr int HW_ = 64 * 128;      // 8192
constexpr int N_  = HW_;           // points per image (near == far == 8192)
constexpr int NX_ = 512;
constexpr int NY_ = 512;
constexpr int NYNX_ = NX_ * NY_;   // 262144
constexpr int SEG_ = 32;           // near-dim segments (partial top-3 per seg)
                                   // 32 -> 2048 blocks = 8 blocks/CU = 32 waves/CU (max occupancy)
constexpr int SEGN_ = N_ / SEG_;   // 256 near candidates per segment (4 KB LDS tile)

// ---------------------------------------------------------------------------
// Pack points. near4/far4: (x,y,z,validflag) for the scatter.
// nearnn: (x,y,z,sq) with sq = |p|^2 in exact numpy-f32 order for valid
// points; masked points are precoded as (0,0,0,1e10f) so the distance formula
// yields sf+1e10 (>= ~1e10, >> max real d2 ~5259) with NO per-candidate
// select. Masked candidates can never enter the final top-3 (~4096 valid
// near points exist), so their sentinel values/tie order are unobservable.
// ---------------------------------------------------------------------------
__global__ __launch_bounds__(256) void pack_kernel(
    const float* __restrict__ pi, const int* __restrict__ pm,
    const float* __restrict__ pif, const int* __restrict__ pmf,
    float4* __restrict__ near4, float4* __restrict__ far4,
    float4* __restrict__ nearnn) {
#pragma clang fp contract(off)
  int t = blockIdx.x * 256 + threadIdx.x;        // over B_*N_
  int k = t / N_, n = t % N_;
  const float* base  = pi  + (size_t)k * 4 * HW_;
  const float* basef = pif + (size_t)k * 4 * HW_;
  float x = base[n], y = base[HW_ + n], z = base[2 * HW_ + n];
  bool v = pm[k * HW_ + n] > 0;
  near4[t] = make_float4(x, y, z, v ? 1.0f : 0.0f);
  float sq = (x * x + y * y) + z * z;   // numpy 3-elem sum order
  nearnn[t] = v ? make_float4(x, y, z, sq)
               : make_float4(0.0f, 0.0f, 0.0f, 1e10f);
  far4[t] = make_float4(basef[n], basef[HW_ + n], basef[2 * HW_ + n],
                        pmf[k * HW_ + n] > 0 ? 1.0f : 0.0f);
}

// ---------------------------------------------------------------------------
// Transpose fv (B,C,HW) -> fvT (B,HW,C).
// ---------------------------------------------------------------------------
__global__ __launch_bounds__(256) void transpose_kernel(
    const float* __restrict__ fv, float* __restrict__ fvT) {
  __shared__ float tile[64][65];
  int tx = threadIdx.x & 63, ty = threadIdx.x >> 6;
  int k = blockIdx.y, n0 = blockIdx.x * 64;
  for (int c = ty; c < C_; c += 4)
    tile[c][tx] = fv[((size_t)(k * C_ + c)) * HW_ + n0 + tx];
  __syncthreads();
  for (int nn = ty; nn < 64; nn += 4)
    fvT[((size_t)(k * HW_ + n0 + nn)) * C_ + tx] = tile[tx][nn];
}

// ---------------------------------------------------------------------------
// Branchless stable insert of (tv, idx) into sorted top-3 (b0<=b1<=b2).
// Exactly reproduces the verified R2 sequential ins3f (jax stable top-k):
//   c0 = tv<b0, c1 = tv<b1, c2 = tv<b2  (c0 => c1 => c2 by sortedness)
//   b0' = c0?tv:b0;  b1' = c0?b0:(c1?tv:b1);  b2' = c1?b1:(c2?tv:b2)
// New candidate LOSES ties (strict <); displaced incumbents shift down
// unconditionally WITH their indices (R3's merge3 got the tie case wrong).
// ---------------------------------------------------------------------------
__device__ __forceinline__ void merge3(float tv, int idx,
                                       float& b0, float& b1, float& b2,
                                       int& i0, int& i1, int& i2) {
  bool c0 = tv < b0;
  bool c1 = tv < b1;
  bool c2 = tv < b2;
  float ob0 = b0, ob1 = b1;
  int   oi0 = i0, oi1 = i1;
  b0 = c0 ? tv : b0;                    i0 = c0 ? idx : i0;
  b1 = c0 ? ob0 : (c1 ? tv : b1);       i1 = c0 ? oi0 : (c1 ? idx : i1);
  b2 = c1 ? ob1 : (c2 ? tv : b2);       i2 = c1 ? oi1 : (c2 ? idx : i2);
}

// ---------------------------------------------------------------------------
// Partial 3-NN: block = (far-block fb, near-segment s, batch k). Each thread
// owns one far point; the 256-candidate segment is staged in LDS and read
// broadcast (conflict-free). d2 replicates the reference f32 arithmetic
// bitwise: (sf + sq_near) - fma(az,qz, fma(ay,qy, ax*qx)). No mask select in
// the loop: masked candidates were precoded to evaluate to ~1e10.
// ---------------------------------------------------------------------------
__global__ __launch_bounds__(256) void nn_part_kernel(
    const float4* __restrict__ nearnn, const float4* __restrict__ far4,
    float* __restrict__ pd, int* __restrict__ pidx) {
#pragma clang fp contract(off)
  __shared__ float4 tile[SEGN_];
  int t = threadIdx.x;
  int fb = blockIdx.x;           // 0..31  far block
  int s  = blockIdx.y;           // 0..SEG_-1
  int k  = blockIdx.z;           // batch

  tile[t] = nearnn[k * N_ + s * SEGN_ + t];
  __syncthreads();

  int m = fb * 256 + t;
  float4 fp = far4[k * N_ + m];
  float fx = fp.x, fy = fp.y, fz = fp.z;
  float sf = (fx * fx + fy * fy) + fz * fz;              // numpy 3-elem order
  float ax = 2.0f * fx, ay = 2.0f * fy, az = 2.0f * fz;  // (2.0*far), exact

  float b0 = 1e30f, b1 = 1e30f, b2 = 1e30f;
  int i0 = 0, i1 = 0, i2 = 0;
  int base_idx = s * SEGN_;
#pragma unroll 8
  for (int i = 0; i < SEGN_; ++i) {
    float4 q = tile[i];
    float p0 = ax * q.x;                                  // round(ax*qx)
    float mm = __builtin_fmaf(az, q.z, __builtin_fmaf(ay, q.y, p0));
    float tv = (sf + q.w) - mm;                           // masked -> ~1e10
    merge3(tv, base_idx + i, b0, b1, b2, i0, i1, i2);
  }

  int o = ((k * N_ + m) * SEG_ + s) * 3;
  pd[o] = b0; pd[o + 1] = b1; pd[o + 2] = b2;
  pidx[o] = i0; pidx[o + 1] = i1; pidx[o + 2] = i2;
}

// ---------------------------------------------------------------------------
// Merge the SEG_ partial top-3 lists per far point (segment-ascending order
// preserves lowest-index tie-breaking) and compute weights exactly as R2.
// ---------------------------------------------------------------------------
__global__ __launch_bounds__(256) void nn_merge_kernel(
    const float* __restrict__ pd, const int* __restrict__ pidx,
    int* __restrict__ nn_idx, float* __restrict__ nn_w) {
#pragma clang fp contract(off)
  int g = blockIdx.x * 256 + threadIdx.x;   // 0..B_*N_-1
  const float* dp = pd + (size_t)g * SEG_ * 3;
  const int*   ip = pidx + (size_t)g * SEG_ * 3;
  float b0 = 1e30f, b1 = 1e30f, b2 = 1e30f;
  int i0 = 0, i1 = 0, i2 = 0;
#pragma unroll 8
  for (int j = 0; j < SEG_ * 3; ++j)
    merge3(dp[j], ip[j], b0, b1, b2, i0, i1, i2);
  float r0 = 1.0f / (b0 + 1e-8f);
  float r1 = 1.0f / (b1 + 1e-8f);
  float r2 = 1.0f / (b2 + 1e-8f);
  float rs = (r0 + r1) + r2;
  int o = g * 3;
  nn_idx[o] = i0; nn_idx[o + 1] = i1; nn_idx[o + 2] = i2;
  nn_w[o] = r0 / rs; nn_w[o + 1] = r1 / rs; nn_w[o + 2] = r2 / rs;
}

// ---------------------------------------------------------------------------
// Scatter-add point features into out (B,C,NY,NX) + counts. One wave per
// point; lane = channel. Voxel binning in f32 IEEE ops, matching numpy.
// ---------------------------------------------------------------------------
__global__ __launch_bounds__(256) void scatter_kernel(
    const float4* __restrict__ near4, const float4* __restrict__ far4,
    const float* __restrict__ fvT,
    const int* __restrict__ nn_idx, const float* __restrict__ nn_w,
    float* __restrict__ out, float* __restrict__ cnt) {
#pragma clang fp contract(off)
  int lane = threadIdx.x & 63;
  int wv = blockIdx.x * 4 + (threadIdx.x >> 6);  // global wave id = point slot
  int k = wv / (2 * N_);
  int p = wv % (2 * N_);
  bool is_far = p >= N_;
  int n = is_far ? p - N_ : p;

  float4 pt = is_far ? far4[k * N_ + n] : near4[k * N_ + n];
  if (pt.w == 0.0f) return;  // invalid: zero weight in reference scatter

  float qx = (pt.x - 0.0f) / 0.1f;
  float qy = (pt.y - (-25.6f)) / 0.1f;
  int ix = (int)floorf(qx);
  int iy = (int)floorf(qy);
  if (ix < 0 || ix >= NX_ || iy < 0 || iy >= NY_) return;
  int v = iy * NX_ + ix;

  float val;
  if (!is_far) {
    val = fvT[((size_t)(k * N_ + n)) * C_ + lane];
  } else {
    int o = (k * N_ + n) * 3;
    int i0 = nn_idx[o], i1 = nn_idx[o + 1], i2 = nn_idx[o + 2];
    float w0 = nn_w[o], w1 = nn_w[o + 1], w2 = nn_w[o + 2];
    val = w0 * fvT[((size_t)(k * N_ + i0)) * C_ + lane]
        + w1 * fvT[((size_t)(k * N_ + i1)) * C_ + lane]
        + w2 * fvT[((size_t)(k * N_ + i2)) * C_ + lane];
  }
  atomicAdd(&out[((size_t)(k * C_ + lane)) * NYNX_ + v], val);
  if (lane == 0) atomicAdd(&cnt[(size_t)k * NYNX_ + v], 1.0f);
}

// ---------------------------------------------------------------------------
// Mean division. cnt in {0,1} -> identity, so only touch cnt >= 2 voxels.
// ---------------------------------------------------------------------------
__global__ __launch_bounds__(256) void finalize_kernel(
    float* __restrict__ out, const float* __restrict__ cnt) {
  int t = blockIdx.x * 256 + threadIdx.x;  // over B_*NYNX_
  int k = t / NYNX_, v = t % NYNX_;
  float c = cnt[(size_t)k * NYNX_ + v];
  if (c >= 2.0f) {
    for (int cc = 0; cc < C_; ++cc)
      out[((size_t)(k * C_ + cc)) * NYNX_ + v] /= c;
  }
}

extern "C" void kernel_launch(void* const* d_in, const int* in_sizes, int n_in,
                              void* d_out, int out_size, void* d_ws, size_t ws_size,
                              hipStream_t stream) {
  const float* fv  = (const float*)d_in[0];  // (B,C,H,W)
  const float* pi  = (const float*)d_in[1];  // (B,4,H,W)
  const int*   pm  = (const int*)d_in[2];    // (B,H,W)
  const float* pif = (const float*)d_in[3];  // (B,4,H,W)
  const int*   pmf = (const int*)d_in[4];    // (B,H,W)
  float* out = (float*)d_out;                // (B,C,NY,NX) f32

  // workspace layout (16B aligned), total ~7.5 MB
  char* wsb = (char*)d_ws;
  float*  fvT    = (float*)(wsb);                 // B*HW*C*4      = 4,194,304
  float*  cnt    = (float*)(wsb + 4194304);       // B*NYNX*4      = 2,097,152
  float4* near4  = (float4*)(wsb + 6291456);      // B*N*16        =   262,144
  float4* far4   = (float4*)(wsb + 6553600);      // B*N*16        =   262,144
  float4* nearnn = (float4*)(wsb + 6815744);      // B*N*16        =   262,144
  int*    nnidx  = (int*)(wsb + 7077888);         // B*N*3*4       =   196,608
  float*  nnw    = (float*)(wsb + 7274496);       // B*N*3*4       =   196,608

  // Partial top-3 buffers live in d_out's head (dead until the memset below):
  // pd: B*N*SEG_*3 floats = 6.29 MB, pidx same in ints (12.6 MB total < 128 MiB).
  float* pd   = out;
  int*   pidx = (int*)(out + (size_t)B_ * N_ * SEG_ * 3);

  pack_kernel<<<B_ * N_ / 256, 256, 0, stream>>>(pi, pm, pif, pmf, near4, far4, nearnn);
  transpose_kernel<<<dim3(HW_ / 64, B_), 256, 0, stream>>>(fv, fvT);
  nn_part_kernel<<<dim3(N_ / 256, SEG_, B_), 256, 0, stream>>>(nearnn, far4, pd, pidx);
  nn_merge_kernel<<<B_ * N_ / 256, 256, 0, stream>>>(pd, pidx, nnidx, nnw);

  hipMemsetAsync(out, 0, (size_t)out_size * sizeof(float), stream);
  hipMemsetAsync(cnt, 0, (size_t)B_ * NYNX_ * sizeof(float), stream);

  scatter_kernel<<<B_ * 2 * N_ / 4, 256, 0, stream>>>(near4, far4, fvT, nnidx, nnw, out, cnt);
  finalize_kernel<<<B_ * NYNX_ / 256, 256, 0, stream>>>(out, cnt);
}

// Round 6
// 264.314 us; speedup vs baseline: 2.4843x; 1.1942x over previous
//
#include <hip/hip_runtime.h>
#include <math.h>

// Problem constants (match the jax reference)
constexpr int B_  = 2;
constexpr int C_  = 64;
constexpr int HW_ = 64 * 128;      // 8192
constexpr int N_  = HW_;           // points per image (near == far == 8192)
constexpr int NX_ = 512;
constexpr int NY_ = 512;
constexpr int NYNX_ = NX_ * NY_;   // 262144
constexpr int SEG_ = 32;           // near-dim segments (partial top-3 per seg)
constexpr int SEGN_ = N_ / SEG_;   // 256 near candidates per segment (4 KB LDS tile)

// ---------------------------------------------------------------------------
// Pack points. near4/far4: (x,y,z,validflag) for the scatter.
// nearnn: (x,y,z,sq); masked points precoded as (0,0,0,1e10f) so the distance
// formula yields ~1e10 with no per-candidate select (they can never win).
// ---------------------------------------------------------------------------
__global__ __launch_bounds__(256) void pack_kernel(
    const float* __restrict__ pi, const int* __restrict__ pm,
    const float* __restrict__ pif, const int* __restrict__ pmf,
    float4* __restrict__ near4, float4* __restrict__ far4,
    float4* __restrict__ nearnn) {
#pragma clang fp contract(off)
  int t = blockIdx.x * 256 + threadIdx.x;        // over B_*N_
  int k = t / N_, n = t % N_;
  const float* base  = pi  + (size_t)k * 4 * HW_;
  const float* basef = pif + (size_t)k * 4 * HW_;
  float x = base[n], y = base[HW_ + n], z = base[2 * HW_ + n];
  bool v = pm[k * HW_ + n] > 0;
  near4[t] = make_float4(x, y, z, v ? 1.0f : 0.0f);
  float sq = (x * x + y * y) + z * z;   // numpy 3-elem sum order
  nearnn[t] = v ? make_float4(x, y, z, sq)
               : make_float4(0.0f, 0.0f, 0.0f, 1e10f);
  far4[t] = make_float4(basef[n], basef[HW_ + n], basef[2 * HW_ + n],
                        pmf[k * HW_ + n] > 0 ? 1.0f : 0.0f);
}

// ---------------------------------------------------------------------------
// Transpose fv (B,C,HW) -> fvT (B,HW,C).
// ---------------------------------------------------------------------------
__global__ __launch_bounds__(256) void transpose_kernel(
    const float* __restrict__ fv, float* __restrict__ fvT) {
  __shared__ float tile[64][65];
  int tx = threadIdx.x & 63, ty = threadIdx.x >> 6;
  int k = blockIdx.y, n0 = blockIdx.x * 64;
  for (int c = ty; c < C_; c += 4)
    tile[c][tx] = fv[((size_t)(k * C_ + c)) * HW_ + n0 + tx];
  __syncthreads();
  for (int nn = ty; nn < 64; nn += 4)
    fvT[((size_t)(k * HW_ + n0 + nn)) * C_ + tx] = tile[tx][nn];
}

// ---------------------------------------------------------------------------
// Branchless stable insert of (tv, idx) into sorted top-3 (b0<=b1<=b2).
// Reproduces jax stable top-k exactly (candidate loses ties; displaced
// incumbents shift down WITH their indices).
// ---------------------------------------------------------------------------
__device__ __forceinline__ void merge3(float tv, int idx,
                                       float& b0, float& b1, float& b2,
                                       int& i0, int& i1, int& i2) {
  bool c0 = tv < b0;
  bool c1 = tv < b1;
  bool c2 = tv < b2;
  float ob0 = b0, ob1 = b1;
  int   oi0 = i0, oi1 = i1;
  b0 = c0 ? tv : b0;                    i0 = c0 ? idx : i0;
  b1 = c0 ? ob0 : (c1 ? tv : b1);       i1 = c0 ? oi0 : (c1 ? idx : i1);
  b2 = c1 ? ob1 : (c2 ? tv : b2);       i2 = c1 ? oi1 : (c2 ? idx : i2);
}

// ---------------------------------------------------------------------------
// Partial 3-NN (unchanged from R5; ~81 us, LDS/VALU co-limited).
// ---------------------------------------------------------------------------
__global__ __launch_bounds__(256) void nn_part_kernel(
    const float4* __restrict__ nearnn, const float4* __restrict__ far4,
    float* __restrict__ pd, int* __restrict__ pidx) {
#pragma clang fp contract(off)
  __shared__ float4 tile[SEGN_];
  int t = threadIdx.x;
  int fb = blockIdx.x;           // 0..31  far block
  int s  = blockIdx.y;           // 0..SEG_-1
  int k  = blockIdx.z;           // batch

  tile[t] = nearnn[k * N_ + s * SEGN_ + t];
  __syncthreads();

  int m = fb * 256 + t;
  float4 fp = far4[k * N_ + m];
  float fx = fp.x, fy = fp.y, fz = fp.z;
  float sf = (fx * fx + fy * fy) + fz * fz;              // numpy 3-elem order
  float ax = 2.0f * fx, ay = 2.0f * fy, az = 2.0f * fz;  // (2.0*far), exact

  float b0 = 1e30f, b1 = 1e30f, b2 = 1e30f;
  int i0 = 0, i1 = 0, i2 = 0;
  int base_idx = s * SEGN_;
#pragma unroll 8
  for (int i = 0; i < SEGN_; ++i) {
    float4 q = tile[i];
    float p0 = ax * q.x;                                  // round(ax*qx)
    float mm = __builtin_fmaf(az, q.z, __builtin_fmaf(ay, q.y, p0));
    float tv = (sf + q.w) - mm;                           // masked -> ~1e10
    merge3(tv, base_idx + i, b0, b1, b2, i0, i1, i2);
  }

  int o = ((k * N_ + m) * SEG_ + s) * 3;
  pd[o] = b0; pd[o + 1] = b1; pd[o + 2] = b2;
  pidx[o] = i0; pidx[o + 1] = i1; pidx[o + 2] = i2;
}

// ---------------------------------------------------------------------------
// Merge the SEG_ partial top-3 lists per far point; weights exactly as ref.
// ---------------------------------------------------------------------------
__global__ __launch_bounds__(256) void nn_merge_kernel(
    const float* __restrict__ pd, const int* __restrict__ pidx,
    int* __restrict__ nn_idx, float* __restrict__ nn_w) {
#pragma clang fp contract(off)
  int g = blockIdx.x * 256 + threadIdx.x;   // 0..B_*N_-1
  const float* dp = pd + (size_t)g * SEG_ * 3;
  const int*   ip = pidx + (size_t)g * SEG_ * 3;
  float b0 = 1e30f, b1 = 1e30f, b2 = 1e30f;
  int i0 = 0, i1 = 0, i2 = 0;
#pragma unroll 8
  for (int j = 0; j < SEG_ * 3; ++j)
    merge3(dp[j], ip[j], b0, b1, b2, i0, i1, i2);
  float r0 = 1.0f / (b0 + 1e-8f);
  float r1 = 1.0f / (b1 + 1e-8f);
  float r2 = 1.0f / (b2 + 1e-8f);
  float rs = (r0 + r1) + r2;
  int o = g * 3;
  nn_idx[o] = i0; nn_idx[o + 1] = i1; nn_idx[o + 2] = i2;
  nn_w[o] = r0 / rs; nn_w[o + 1] = r1 / rs; nn_w[o + 2] = r2 / rs;
}

// ---------------------------------------------------------------------------
// Shared voxel binning (numpy f32 bitwise). Returns -1 if point contributes
// nothing (invalid or out of range).
// ---------------------------------------------------------------------------
__device__ __forceinline__ int voxel_of(float4 pt) {
#pragma clang fp contract(off)
  if (pt.w == 0.0f) return -1;
  float qx = (pt.x - 0.0f) / 0.1f;
  float qy = (pt.y - (-25.6f)) / 0.1f;
  int ix = (int)floorf(qx);
  int iy = (int)floorf(qy);
  if (ix < 0 || ix >= NX_ || iy < 0 || iy >= NY_) return -1;
  return iy * NX_ + ix;
}

// ---------------------------------------------------------------------------
// Pass 1: per-voxel point counts (1 atomic per valid point, ~16K ops).
// ---------------------------------------------------------------------------
__global__ __launch_bounds__(256) void count_kernel(
    const float4* __restrict__ near4, const float4* __restrict__ far4,
    float* __restrict__ cnt) {
  int t = blockIdx.x * 256 + threadIdx.x;  // over B_*2*N_
  int k = t / (2 * N_);
  int p = t % (2 * N_);
  float4 pt = (p < N_) ? near4[k * N_ + p] : far4[k * N_ + p - N_];
  int v = voxel_of(pt);
  if (v >= 0) atomicAdd(&cnt[(size_t)k * NYNX_ + v], 1.0f);
}

// ---------------------------------------------------------------------------
// Pass 2: zero acc rows only where cnt>=2 (~130 voxels/batch). Singleton rows
// are fully overwritten by stores; empty rows are never read.
// ---------------------------------------------------------------------------
__global__ __launch_bounds__(256) void zero_coll_kernel(
    const float* __restrict__ cnt, float* __restrict__ acc) {
  int t = blockIdx.x * 256 + threadIdx.x;  // over B_*NYNX_ (flat (k,v))
  if (cnt[t] >= 2.0f) {
    float4* row = (float4*)(acc + (size_t)t * C_);
    float4 z = make_float4(0.0f, 0.0f, 0.0f, 0.0f);
    for (int i = 0; i < C_ / 4; ++i) row[i] = z;
  }
}

// ---------------------------------------------------------------------------
// Pass 3: scatter features into voxel-major acc (k,v,C). Wave per point,
// lane = channel -> 256 B coalesced row. cnt==1 (98%): plain store (no RMW,
// no init needed). cnt>=2: row-coalesced atomics into pre-zeroed row.
// ---------------------------------------------------------------------------
__global__ __launch_bounds__(256) void scatter_feat_kernel(
    const float4* __restrict__ near4, const float4* __restrict__ far4,
    const float* __restrict__ fvT,
    const int* __restrict__ nn_idx, const float* __restrict__ nn_w,
    const float* __restrict__ cnt, float* __restrict__ acc) {
#pragma clang fp contract(off)
  int lane = threadIdx.x & 63;
  int wv = blockIdx.x * 4 + (threadIdx.x >> 6);  // global wave id = point slot
  int k = wv / (2 * N_);
  int p = wv % (2 * N_);
  bool is_far = p >= N_;
  int n = is_far ? p - N_ : p;

  float4 pt = is_far ? far4[k * N_ + n] : near4[k * N_ + n];
  int v = voxel_of(pt);
  if (v < 0) return;

  float val;
  if (!is_far) {
    val = fvT[((size_t)(k * N_ + n)) * C_ + lane];
  } else {
    int o = (k * N_ + n) * 3;
    int i0 = nn_idx[o], i1 = nn_idx[o + 1], i2 = nn_idx[o + 2];
    float w0 = nn_w[o], w1 = nn_w[o + 1], w2 = nn_w[o + 2];
    val = w0 * fvT[((size_t)(k * N_ + i0)) * C_ + lane]
        + w1 * fvT[((size_t)(k * N_ + i1)) * C_ + lane]
        + w2 * fvT[((size_t)(k * N_ + i2)) * C_ + lane];
  }
  size_t rowoff = ((size_t)k * NYNX_ + v) * C_;
  float cn = cnt[(size_t)k * NYNX_ + v];   // wave-uniform
  if (cn == 1.0f) acc[rowoff + lane] = val;
  else            atomicAdd(&acc[rowoff + lane], val);
}

// ---------------------------------------------------------------------------
// Pass 4: emit out (B,C,NY,NX) from acc/cnt. Coalesced float4 stores cover
// every element exactly once (fuses the zero-fill); acc gathers happen only
// under real branches for occupied voxels (~6%); divide = sums/max(cnt,1).
// ---------------------------------------------------------------------------
__global__ __launch_bounds__(256) void emit_kernel(
    const float* __restrict__ acc, const float* __restrict__ cnt,
    float* __restrict__ out) {
#pragma clang fp contract(off)
  int t = blockIdx.x * 256 + threadIdx.x;        // over B_*C_*NYNX_/4
  constexpr int VQ = NYNX_ / 4;
  int vq = t % VQ;
  int c  = (t / VQ) % C_;
  int k  = t / (C_ * VQ);
  float4 cn = ((const float4*)(cnt + (size_t)k * NYNX_))[vq];
  const float* abase = acc + ((size_t)k * NYNX_ + (size_t)vq * 4) * C_ + c;
  float4 o = make_float4(0.0f, 0.0f, 0.0f, 0.0f);
  if (cn.x > 0.0f) o.x = abase[0 * C_] / cn.x;
  if (cn.y > 0.0f) o.y = abase[1 * C_] / cn.y;
  if (cn.z > 0.0f) o.z = abase[2 * C_] / cn.z;
  if (cn.w > 0.0f) o.w = abase[3 * C_] / cn.w;
  ((float4*)out)[t] = o;
}

extern "C" void kernel_launch(void* const* d_in, const int* in_sizes, int n_in,
                              void* d_out, int out_size, void* d_ws, size_t ws_size,
                              hipStream_t stream) {
  const float* fv  = (const float*)d_in[0];  // (B,C,H,W)
  const float* pi  = (const float*)d_in[1];  // (B,4,H,W)
  const int*   pm  = (const int*)d_in[2];    // (B,H,W)
  const float* pif = (const float*)d_in[3];  // (B,4,H,W)
  const int*   pmf = (const int*)d_in[4];    // (B,H,W)
  float* out = (float*)d_out;                // (B,C,NY,NX) f32

  // workspace layout (16B aligned): small buffers ~7.5 MB, acc 134 MB at +8MB.
  char* wsb = (char*)d_ws;
  float*  fvT    = (float*)(wsb);                 // B*HW*C*4      = 4,194,304
  float*  cnt    = (float*)(wsb + 4194304);       // B*NYNX*4      = 2,097,152
  float4* near4  = (float4*)(wsb + 6291456);      // B*N*16        =   262,144
  float4* far4   = (float4*)(wsb + 6553600);      // B*N*16        =   262,144
  float4* nearnn = (float4*)(wsb + 6815744);      // B*N*16        =   262,144
  int*    nnidx  = (int*)(wsb + 7077888);         // B*N*3*4       =   196,608
  float*  nnw    = (float*)(wsb + 7274496);       // B*N*3*4       =   196,608
  float*  acc    = (float*)(wsb + 8388608);       // B*NYNX*C*4    = 134,217,728

  // Partial top-3 buffers live in d_out's head (consumed by nn_merge before
  // emit overwrites out): pd 6.29 MB + pidx 6.29 MB.
  float* pd   = out;
  int*   pidx = (int*)(out + (size_t)B_ * N_ * SEG_ * 3);

  hipMemsetAsync(cnt, 0, (size_t)B_ * NYNX_ * sizeof(float), stream);

  pack_kernel<<<B_ * N_ / 256, 256, 0, stream>>>(pi, pm, pif, pmf, near4, far4, nearnn);
  transpose_kernel<<<dim3(HW_ / 64, B_), 256, 0, stream>>>(fv, fvT);
  nn_part_kernel<<<dim3(N_ / 256, SEG_, B_), 256, 0, stream>>>(nearnn, far4, pd, pidx);
  nn_merge_kernel<<<B_ * N_ / 256, 256, 0, stream>>>(pd, pidx, nnidx, nnw);

  count_kernel<<<B_ * 2 * N_ / 256, 256, 0, stream>>>(near4, far4, cnt);
  zero_coll_kernel<<<B_ * NYNX_ / 256, 256, 0, stream>>>(cnt, acc);
  scatter_feat_kernel<<<B_ * 2 * N_ / 4, 256, 0, stream>>>(near4, far4, fvT, nnidx, nnw, cnt, acc);
  emit_kernel<<<B_ * C_ * NYNX_ / 4 / 256, 256, 0, stream>>>(acc, cnt, out);
}

// Round 7
// 242.388 us; speedup vs baseline: 2.7090x; 1.0905x over previous
//
#include <hip/hip_runtime.h>
#include <math.h>

// Problem constants (match the jax reference)
constexpr int B_  = 2;
constexpr int C_  = 64;
constexpr int HW_ = 64 * 128;      // 8192
constexpr int N_  = HW_;           // points per image (near == far == 8192)
constexpr int NX_ = 512;
constexpr int NY_ = 512;
constexpr int NYNX_ = NX_ * NY_;   // 262144
constexpr int SEG_  = 64;          // near-dim segments (partial top-3 per seg)
constexpr int SEGN_ = N_ / SEG_;   // 128 near candidates per segment (2 KB tile)
constexpr int FPT_  = 2;           // far points per thread in nn_part
constexpr int BN_   = B_ * N_;     // 16384

// ---------------------------------------------------------------------------
// Shared voxel binning (numpy f32 bitwise). -1 = contributes nothing.
// ---------------------------------------------------------------------------
__device__ __forceinline__ int voxel_of(float x, float y, float w) {
#pragma clang fp contract(off)
  if (w == 0.0f) return -1;
  float qx = (x - 0.0f) / 0.1f;
  float qy = (y - (-25.6f)) / 0.1f;
  int ix = (int)floorf(qx);
  int iy = (int)floorf(qy);
  if (ix < 0 || ix >= NX_ || iy < 0 || iy >= NY_) return -1;
  return iy * NX_ + ix;
}

// ---------------------------------------------------------------------------
// Pack points + fused per-voxel counting (1 atomic per valid point).
// nearnn: (x,y,z,sq); masked precoded (0,0,0,1e10f) -> d2 ~1e10, never wins.
// ---------------------------------------------------------------------------
__global__ __launch_bounds__(256) void pack_count_kernel(
    const float* __restrict__ pi, const int* __restrict__ pm,
    const float* __restrict__ pif, const int* __restrict__ pmf,
    float4* __restrict__ near4, float4* __restrict__ far4,
    float4* __restrict__ nearnn, float* __restrict__ cnt) {
#pragma clang fp contract(off)
  int t = blockIdx.x * 256 + threadIdx.x;        // over B_*N_
  int k = t / N_, n = t % N_;
  const float* base  = pi  + (size_t)k * 4 * HW_;
  const float* basef = pif + (size_t)k * 4 * HW_;
  float x = base[n], y = base[HW_ + n], z = base[2 * HW_ + n];
  bool v = pm[k * HW_ + n] > 0;
  near4[t] = make_float4(x, y, z, v ? 1.0f : 0.0f);
  float sq = (x * x + y * y) + z * z;   // numpy 3-elem sum order
  nearnn[t] = v ? make_float4(x, y, z, sq)
               : make_float4(0.0f, 0.0f, 0.0f, 1e10f);
  float fx = basef[n], fy = basef[HW_ + n], fz = basef[2 * HW_ + n];
  bool vf = pmf[k * HW_ + n] > 0;
  far4[t] = make_float4(fx, fy, fz, vf ? 1.0f : 0.0f);

  int vn = voxel_of(x, y, v ? 1.0f : 0.0f);
  if (vn >= 0) atomicAdd(&cnt[(size_t)k * NYNX_ + vn], 1.0f);
  int vfv = voxel_of(fx, fy, vf ? 1.0f : 0.0f);
  if (vfv >= 0) atomicAdd(&cnt[(size_t)k * NYNX_ + vfv], 1.0f);
}

// ---------------------------------------------------------------------------
// Transpose fv (B,C,HW) -> fvT (B,HW,C).
// ---------------------------------------------------------------------------
__global__ __launch_bounds__(256) void transpose_kernel(
    const float* __restrict__ fv, float* __restrict__ fvT) {
  __shared__ float tile[64][65];
  int tx = threadIdx.x & 63, ty = threadIdx.x >> 6;
  int k = blockIdx.y, n0 = blockIdx.x * 64;
  for (int c = ty; c < C_; c += 4)
    tile[c][tx] = fv[((size_t)(k * C_ + c)) * HW_ + n0 + tx];
  __syncthreads();
  for (int nn = ty; nn < 64; nn += 4)
    fvT[((size_t)(k * HW_ + n0 + nn)) * C_ + tx] = tile[tx][nn];
}

// ---------------------------------------------------------------------------
// Stable top-3 insert, split into value path (min + 2x med3) and index path
// (3 cmp + 5 cndmask). Case-exhaustively identical to the verified merge3:
// candidate loses ties; displaced incumbents shift down with their indices.
// ---------------------------------------------------------------------------
__device__ __forceinline__ void merge3_fast(float tv, int idx,
                                            float& b0, float& b1, float& b2,
                                            int& i0, int& i1, int& i2) {
  bool c0 = tv < b0;
  bool c1 = tv < b1;
  bool c2 = tv < b2;
  float nb0 = fminf(b0, tv);
  float nb1 = __builtin_amdgcn_fmed3f(b0, b1, tv);
  float nb2 = __builtin_amdgcn_fmed3f(b1, b2, tv);
  int oi0 = i0, oi1 = i1;
  i0 = c0 ? idx : i0;
  i1 = c0 ? oi0 : (c1 ? idx : i1);
  i2 = c1 ? oi1 : (c2 ? idx : i2);
  b0 = nb0; b1 = nb1; b2 = nb2;
}

// Full cndmask variant (used in merges where op count doesn't matter).
__device__ __forceinline__ void merge3(float tv, int idx,
                                       float& b0, float& b1, float& b2,
                                       int& i0, int& i1, int& i2) {
  bool c0 = tv < b0;
  bool c1 = tv < b1;
  bool c2 = tv < b2;
  float ob0 = b0, ob1 = b1;
  int   oi0 = i0, oi1 = i1;
  b0 = c0 ? tv : b0;                    i0 = c0 ? idx : i0;
  b1 = c0 ? ob0 : (c1 ? tv : b1);       i1 = c0 ? oi0 : (c1 ? idx : i1);
  b2 = c1 ? ob1 : (c2 ? tv : b2);       i2 = c1 ? oi1 : (c2 ? idx : i2);
}

// ---------------------------------------------------------------------------
// Partial 3-NN: 2 far points per thread; 128-candidate LDS tile (broadcast
// reads, conflict-free). d2 replicates reference f32 bitwise:
// (sf + sq_near) - fma(az,qz, fma(ay,qy, ax*qx)).
// Partials stored SEGMENT-MAJOR: pd[(s*3+slot)*BN + g] for coalesced merge.
// ---------------------------------------------------------------------------
__global__ __launch_bounds__(256, 8) void nn_part_kernel(
    const float4* __restrict__ nearnn, const float4* __restrict__ far4,
    float* __restrict__ pd, int* __restrict__ pidx) {
#pragma clang fp contract(off)
  __shared__ float4 tile[SEGN_];
  int t = threadIdx.x;
  int fb = blockIdx.x;           // 0..15  far block (512 far points each)
  int s  = blockIdx.y;           // 0..SEG_-1
  int k  = blockIdx.z;           // batch

  if (t < SEGN_) tile[t] = nearnn[k * N_ + s * SEGN_ + t];
  __syncthreads();

  int m0 = fb * (256 * FPT_) + t;
  int m1 = m0 + 256;
  float4 f0 = far4[k * N_ + m0];
  float4 f1 = far4[k * N_ + m1];
  float sf0 = (f0.x * f0.x + f0.y * f0.y) + f0.z * f0.z;  // numpy 3-elem order
  float sf1 = (f1.x * f1.x + f1.y * f1.y) + f1.z * f1.z;
  float ax0 = 2.0f * f0.x, ay0 = 2.0f * f0.y, az0 = 2.0f * f0.z;
  float ax1 = 2.0f * f1.x, ay1 = 2.0f * f1.y, az1 = 2.0f * f1.z;

  float a0 = 1e30f, a1 = 1e30f, a2 = 1e30f;
  float b0 = 1e30f, b1 = 1e30f, b2 = 1e30f;
  int ia0 = 0, ia1 = 0, ia2 = 0;
  int ib0 = 0, ib1 = 0, ib2 = 0;
  int base_idx = s * SEGN_;
#pragma unroll 4
  for (int i = 0; i < SEGN_; ++i) {
    float4 q = tile[i];
    int idx = base_idx + i;
    float p0 = ax0 * q.x;                                  // round(ax*qx)
    float mm0 = __builtin_fmaf(az0, q.z, __builtin_fmaf(ay0, q.y, p0));
    float tv0 = (sf0 + q.w) - mm0;                         // masked -> ~1e10
    merge3_fast(tv0, idx, a0, a1, a2, ia0, ia1, ia2);
    float p1 = ax1 * q.x;
    float mm1 = __builtin_fmaf(az1, q.z, __builtin_fmaf(ay1, q.y, p1));
    float tv1 = (sf1 + q.w) - mm1;
    merge3_fast(tv1, idx, b0, b1, b2, ib0, ib1, ib2);
  }

  int g0 = k * N_ + m0, g1 = k * N_ + m1;
  int jb = s * 3;
  pd[(size_t)(jb + 0) * BN_ + g0] = a0;
  pd[(size_t)(jb + 1) * BN_ + g0] = a1;
  pd[(size_t)(jb + 2) * BN_ + g0] = a2;
  pidx[(size_t)(jb + 0) * BN_ + g0] = ia0;
  pidx[(size_t)(jb + 1) * BN_ + g0] = ia1;
  pidx[(size_t)(jb + 2) * BN_ + g0] = ia2;
  pd[(size_t)(jb + 0) * BN_ + g1] = b0;
  pd[(size_t)(jb + 1) * BN_ + g1] = b1;
  pd[(size_t)(jb + 2) * BN_ + g1] = b2;
  pidx[(size_t)(jb + 0) * BN_ + g1] = ib0;
  pidx[(size_t)(jb + 1) * BN_ + g1] = ib1;
  pidx[(size_t)(jb + 2) * BN_ + g1] = ib2;
}

// ---------------------------------------------------------------------------
// Merge SEG_*3 = 192 partials per far point. 4 threads per far point, each
// merging a CONTIGUOUS j-range (ascending j = ascending segment = ascending
// index base, preserving the lowest-index tie rule), then combine in q order
// via LDS. Reads are coalesced (segment-major layout, lanes = consecutive g).
// ---------------------------------------------------------------------------
__global__ __launch_bounds__(256) void nn_merge_kernel(
    const float* __restrict__ pd, const int* __restrict__ pidx,
    int* __restrict__ nn_idx, float* __restrict__ nn_w) {
#pragma clang fp contract(off)
  constexpr int Q = 4;                   // threads per far point
  constexpr int J = SEG_ * 3 / Q;        // 48 candidates per thread
  __shared__ float md[Q][64][3];
  __shared__ int   mi[Q][64][3];
  int t = threadIdx.x;
  int q  = t >> 6;                       // 0..3
  int gl = t & 63;
  int g = blockIdx.x * 64 + gl;          // far point id (over BN_)

  float b0 = 1e30f, b1 = 1e30f, b2 = 1e30f;
  int i0 = 0, i1 = 0, i2 = 0;
  int j0 = q * J;
  for (int j = 0; j < J; ++j) {
    float d = pd[(size_t)(j0 + j) * BN_ + g];
    int   ix = pidx[(size_t)(j0 + j) * BN_ + g];
    merge3(d, ix, b0, b1, b2, i0, i1, i2);
  }
  md[q][gl][0] = b0; md[q][gl][1] = b1; md[q][gl][2] = b2;
  mi[q][gl][0] = i0; mi[q][gl][1] = i1; mi[q][gl][2] = i2;
  __syncthreads();

  if (q == 0) {
    float c0 = 1e30f, c1 = 1e30f, c2 = 1e30f;
    int k0 = 0, k1 = 0, k2 = 0;
    for (int qq = 0; qq < Q; ++qq)
      for (int j = 0; j < 3; ++j)
        merge3(md[qq][gl][j], mi[qq][gl][j], c0, c1, c2, k0, k1, k2);
    float r0 = 1.0f / (c0 + 1e-8f);
    float r1 = 1.0f / (c1 + 1e-8f);
    float r2 = 1.0f / (c2 + 1e-8f);
    float rs = (r0 + r1) + r2;
    int o = g * 3;
    nn_idx[o] = k0; nn_idx[o + 1] = k1; nn_idx[o + 2] = k2;
    nn_w[o] = r0 / rs; nn_w[o + 1] = r1 / rs; nn_w[o + 2] = r2 / rs;
  }
}

// ---------------------------------------------------------------------------
// Zero acc rows only where cnt>=2 (~130 voxels/batch).
// ---------------------------------------------------------------------------
__global__ __launch_bounds__(256) void zero_coll_kernel(
    const float* __restrict__ cnt, float* __restrict__ acc) {
  int t = blockIdx.x * 256 + threadIdx.x;  // over B_*NYNX_ (flat (k,v))
  if (cnt[t] >= 2.0f) {
    float4* row = (float4*)(acc + (size_t)t * C_);
    float4 z = make_float4(0.0f, 0.0f, 0.0f, 0.0f);
    for (int i = 0; i < C_ / 4; ++i) row[i] = z;
  }
}

// ---------------------------------------------------------------------------
// Scatter features into voxel-major acc (k,v,C). Wave per point, lane =
// channel. cnt==1 (98%): plain coalesced store. cnt>=2: row atomics.
// ---------------------------------------------------------------------------
__global__ __launch_bounds__(256) void scatter_feat_kernel(
    const float4* __restrict__ near4, const float4* __restrict__ far4,
    const float* __restrict__ fvT,
    const int* __restrict__ nn_idx, const float* __restrict__ nn_w,
    const float* __restrict__ cnt, float* __restrict__ acc) {
#pragma clang fp contract(off)
  int lane = threadIdx.x & 63;
  int wv = blockIdx.x * 4 + (threadIdx.x >> 6);  // global wave id = point slot
  int k = wv / (2 * N_);
  int p = wv % (2 * N_);
  bool is_far = p >= N_;
  int n = is_far ? p - N_ : p;

  float4 pt = is_far ? far4[k * N_ + n] : near4[k * N_ + n];
  int v = voxel_of(pt.x, pt.y, pt.w);
  if (v < 0) return;

  float val;
  if (!is_far) {
    val = fvT[((size_t)(k * N_ + n)) * C_ + lane];
  } else {
    int o = (k * N_ + n) * 3;
    int i0 = nn_idx[o], i1 = nn_idx[o + 1], i2 = nn_idx[o + 2];
    float w0 = nn_w[o], w1 = nn_w[o + 1], w2 = nn_w[o + 2];
    val = w0 * fvT[((size_t)(k * N_ + i0)) * C_ + lane]
        + w1 * fvT[((size_t)(k * N_ + i1)) * C_ + lane]
        + w2 * fvT[((size_t)(k * N_ + i2)) * C_ + lane];
  }
  size_t rowoff = ((size_t)k * NYNX_ + v) * C_;
  float cn = cnt[(size_t)k * NYNX_ + v];   // wave-uniform
  if (cn == 1.0f) acc[rowoff + lane] = val;
  else            atomicAdd(&acc[rowoff + lane], val);
}

// ---------------------------------------------------------------------------
// Emit out (B,C,NY,NX) from acc/cnt via LDS transpose. Per block: 64 voxels.
// Phase 1: coalesced float4 row-gathers of occupied rows (divide fused),
// zeros otherwise, into tile[c][row]. Phase 2: coalesced float4 out stores.
// Covers every out element exactly once (fuses the zero-fill).
// ---------------------------------------------------------------------------
__global__ __launch_bounds__(256) void emit_kernel(
    const float* __restrict__ acc, const float* __restrict__ cnt,
    float* __restrict__ out) {
#pragma clang fp contract(off)
  __shared__ float tile[64][65];
  __shared__ float cs[64];
  int t = threadIdx.x;
  int k = blockIdx.y;
  int v0 = blockIdx.x * 64;

  if (t < 64) cs[t] = cnt[(size_t)k * NYNX_ + v0 + t];
  __syncthreads();

  const float4* acc4 = (const float4*)acc;
#pragma unroll
  for (int p = 0; p < 4; ++p) {
    int row = p * 16 + (t >> 4);     // voxel within block
    int f4  = t & 15;                // float4 within the 64-channel row
    float c = cs[row];
    float4 a = make_float4(0.0f, 0.0f, 0.0f, 0.0f);
    if (c > 0.0f) {
      a = acc4[((size_t)k * NYNX_ + v0 + row) * (C_ / 4) + f4];
      a.x /= c; a.y /= c; a.z /= c; a.w /= c;
    }
    tile[f4 * 4 + 0][row] = a.x;
    tile[f4 * 4 + 1][row] = a.y;
    tile[f4 * 4 + 2][row] = a.z;
    tile[f4 * 4 + 3][row] = a.w;
  }
  __syncthreads();

#pragma unroll
  for (int p = 0; p < 4; ++p) {
    int c  = p * 16 + (t >> 4);      // channel
    int xq = t & 15;                 // float4 of voxels
    float4 o = make_float4(tile[c][xq * 4 + 0], tile[c][xq * 4 + 1],
                           tile[c][xq * 4 + 2], tile[c][xq * 4 + 3]);
    ((float4*)out)[(((size_t)k * C_ + c) * NYNX_ + v0) / 4 + xq] = o;
  }
}

extern "C" void kernel_launch(void* const* d_in, const int* in_sizes, int n_in,
                              void* d_out, int out_size, void* d_ws, size_t ws_size,
                              hipStream_t stream) {
  const float* fv  = (const float*)d_in[0];  // (B,C,H,W)
  const float* pi  = (const float*)d_in[1];  // (B,4,H,W)
  const int*   pm  = (const int*)d_in[2];    // (B,H,W)
  const float* pif = (const float*)d_in[3];  // (B,4,H,W)
  const int*   pmf = (const int*)d_in[4];    // (B,H,W)
  float* out = (float*)d_out;                // (B,C,NY,NX) f32

  // workspace layout (16B aligned): small buffers ~7.5 MB, acc 134 MB at +8MB.
  char* wsb = (char*)d_ws;
  float*  fvT    = (float*)(wsb);                 // B*HW*C*4      = 4,194,304
  float*  cnt    = (float*)(wsb + 4194304);       // B*NYNX*4      = 2,097,152
  float4* near4  = (float4*)(wsb + 6291456);      // B*N*16        =   262,144
  float4* far4   = (float4*)(wsb + 6553600);      // B*N*16        =   262,144
  float4* nearnn = (float4*)(wsb + 6815744);      // B*N*16        =   262,144
  int*    nnidx  = (int*)(wsb + 7077888);         // B*N*3*4       =   196,608
  float*  nnw    = (float*)(wsb + 7274496);       // B*N*3*4       =   196,608
  float*  acc    = (float*)(wsb + 8388608);       // B*NYNX*C*4    = 134,217,728

  // Partial top-3 buffers live in d_out's head (consumed by nn_merge before
  // emit overwrites out): pd 12.6 MB + pidx 12.6 MB (segment-major).
  float* pd   = out;
  int*   pidx = (int*)(out + (size_t)SEG_ * 3 * BN_);

  hipMemsetAsync(cnt, 0, (size_t)B_ * NYNX_ * sizeof(float), stream);

  pack_count_kernel<<<B_ * N_ / 256, 256, 0, stream>>>(
      pi, pm, pif, pmf, near4, far4, nearnn, cnt);
  transpose_kernel<<<dim3(HW_ / 64, B_), 256, 0, stream>>>(fv, fvT);
  nn_part_kernel<<<dim3(N_ / (256 * FPT_), SEG_, B_), 256, 0, stream>>>(
      nearnn, far4, pd, pidx);
  nn_merge_kernel<<<BN_ / 64, 256, 0, stream>>>(pd, pidx, nnidx, nnw);

  zero_coll_kernel<<<B_ * NYNX_ / 256, 256, 0, stream>>>(cnt, acc);
  scatter_feat_kernel<<<B_ * 2 * N_ / 4, 256, 0, stream>>>(
      near4, far4, fvT, nnidx, nnw, cnt, acc);
  emit_kernel<<<dim3(NYNX_ / 64, B_), 256, 0, stream>>>(acc, cnt, out);
}